// Round 4
// baseline (1464.197 us; speedup 1.0000x reference)
//
#include <hip/hip_runtime.h>
#include <cstdint>

// ---------------- constants ----------------
#define NFFT   131072
#define BROWS  32
#define PLEN   131071
#define NWORDS 2048       // 64-bit words per row of edge bits
#define CAPC   16384      // candidate / kept capacity per row

// ================= twiddle table: tw[t] = (cos, sin)(2*pi*t/N) =================
__global__ __launch_bounds__(256) void setup_tw(double2* __restrict__ tw) {
    int t = blockIdx.x * 256 + threadIdx.x;           // [0, 131072)
    double ang = 6.283185307179586476925286766559 * ((double)t / 131072.0);
    double s, c;
    sincos(ang, &s, &c);
    tw[t] = make_double2(c, s);
}

// ================= scratch init (capture-safe, replaces hipMemsetAsync) =========
__global__ __launch_bounds__(256) void init_scratch(int* __restrict__ firstm,
                                                    int* __restrict__ cnt) {
    int i = blockIdx.x * 256 + threadIdx.x;           // 4,194,304 ints
    firstm[i] = 0x7F7F7F7F;                           // BIG sentinel for scatter-min
    if (i < 64) cnt[i] = 0;                           // cnt[32] + kcnt[32]
}

__global__ __launch_bounds__(256) void zero_out(float* __restrict__ out, int n) {
    int i = blockIdx.x * 256 + threadIdx.x;
    if (i < n) out[i] = 0.0f;
}

// ================= FFT pass 1: 256-pt strided + inter-pass twiddle ==============
// Four-step N = 512*256, n = n2*512 + n1.  Inner DFT over n2 (len 256) for each
// column n1, multiply W_N^{DIR*n1*k2}, store Y[k2*512 + n1].
// DIR = -1: forward, real input x.   DIR = +1: inverse, complex input Zt where
// Zt[k2*512+k1] holds Z[k1*256+k2]  (so Z[m2*512+m1] = Zt[(m1&255)*512 + 2*m2 + (m1>>8)]).
template<int DIR, typename CT>
__global__ __launch_bounds__(256) void fft_pass1(const float* __restrict__ xin,
                                                 const CT* __restrict__ zin,
                                                 CT* __restrict__ yout,
                                                 const double2* __restrict__ tw) {
    constexpr int L = 256, FPB = 4, T = 64, LH = 128;
    __shared__ double2 bufA[FPB][L];
    __shared__ double2 bufB[FPB][L];
    __shared__ double2 twL[255];
    const int b   = blockIdx.y;
    const int f   = threadIdx.x >> 6;
    const int tl  = threadIdx.x & 63;
    const int col = blockIdx.x * FPB + f;             // n1 / m1 in [0,512)

    if (threadIdx.x < 255) {                          // stage twiddles: twL[Ns-1+js]
        int ip = threadIdx.x + 1;
        int s  = 31 - __clz(ip);
        int js = ip - (1 << s);
        twL[threadIdx.x] = tw[js << (16 - s)];        // angle = pi*js/Ns
    }
    if constexpr (DIR == -1) {
        const float* xr = xin + (size_t)b * NFFT;
        for (int r = 0; r < L / T; ++r) {
            int n2 = tl + r * T;
            bufA[f][n2] = make_double2((double)xr[n2 * 512 + col], 0.0);
        }
    } else {
        const CT* zr = zin + (size_t)b * NFFT;
        int c1l = col & 255, c1h = col >> 8;
        for (int r = 0; r < L / T; ++r) {
            int m2 = tl + r * T;
            CT v = zr[c1l * 512 + 2 * m2 + c1h];
            bufA[f][m2] = make_double2((double)v.x, (double)v.y);
        }
    }
    __syncthreads();

    double2* src = bufA[f];
    double2* dst = bufB[f];
    int Ns = 1;
#pragma unroll
    for (int it = 0; it < 8; ++it) {
#pragma unroll
        for (int jj = 0; jj < LH / T; ++jj) {
            int j  = tl + jj * T;
            int js = j & (Ns - 1);
            double2 w = twL[Ns - 1 + js];
            double ws_ = (DIR < 0) ? -w.y : w.y;
            double2 v0 = src[j];
            double2 v1 = src[j + LH];
            double wr = v1.x * w.x - v1.y * ws_;
            double wi = v1.x * ws_ + v1.y * w.x;
            int idxD = ((j - js) << 1) + js;
            dst[idxD]      = make_double2(v0.x + wr, v0.y + wi);
            dst[idxD + Ns] = make_double2(v0.x - wr, v0.y - wi);
        }
        __syncthreads();
        double2* t2 = src; src = dst; dst = t2;
        Ns <<= 1;
    }
    // 8 iterations -> result back in bufA[f] (== src)
    CT* yr = yout + (size_t)b * NFFT;
    for (int r = 0; r < L / T; ++r) {
        int k2 = tl + r * T;
        int t  = (col * k2) & (NFFT - 1);
        double2 w = tw[t];
        double ws_ = (DIR < 0) ? -w.y : w.y;
        double2 v = src[k2];
        CT o;
        o.x = (decltype(o.x))(v.x * w.x - v.y * ws_);
        o.y = (decltype(o.y))(v.x * ws_ + v.y * w.x);
        yr[k2 * 512 + col] = o;
    }
}

// ================= FFT pass 2: 512-pt contiguous ==============
// DIR=-1: apply analytic-filter h(k), write Zt[k2*512+k1].
// DIR=+1: write env[c1*256+c2] = |a|/N (float).
template<int DIR, typename CT>
__global__ __launch_bounds__(256) void fft_pass2(const CT* __restrict__ yin,
                                                 CT* __restrict__ ztout,
                                                 float* __restrict__ envout,
                                                 const double2* __restrict__ tw) {
    constexpr int L = 512, FPB = 2, T = 128, LH = 256;
    __shared__ double2 bufA[FPB][L];
    __shared__ double2 bufB[FPB][L];
    __shared__ double2 twL[511];
    const int b  = blockIdx.y;
    const int f  = threadIdx.x >> 7;
    const int tl = threadIdx.x & 127;
    const int k2 = blockIdx.x * FPB + f;              // [0,256)

    for (int i = threadIdx.x; i < 511; i += 256) {
        int ip = i + 1;
        int s  = 31 - __clz(ip);
        int js = ip - (1 << s);
        twL[i] = tw[js << (16 - s)];
    }
    const CT* yr = yin + (size_t)b * NFFT + (size_t)k2 * 512;
    for (int r = 0; r < L / T; ++r) {
        int i = tl + r * T;
        CT v = yr[i];
        bufA[f][i] = make_double2((double)v.x, (double)v.y);
    }
    __syncthreads();

    double2* src = bufA[f];
    double2* dst = bufB[f];
    int Ns = 1;
#pragma unroll
    for (int it = 0; it < 9; ++it) {
#pragma unroll
        for (int jj = 0; jj < LH / T; ++jj) {
            int j  = tl + jj * T;
            int js = j & (Ns - 1);
            double2 w = twL[Ns - 1 + js];
            double ws_ = (DIR < 0) ? -w.y : w.y;
            double2 v0 = src[j];
            double2 v1 = src[j + LH];
            double wr = v1.x * w.x - v1.y * ws_;
            double wi = v1.x * ws_ + v1.y * w.x;
            int idxD = ((j - js) << 1) + js;
            dst[idxD]      = make_double2(v0.x + wr, v0.y + wi);
            dst[idxD + Ns] = make_double2(v0.x - wr, v0.y - wi);
        }
        __syncthreads();
        double2* t2 = src; src = dst; dst = t2;
        Ns <<= 1;
    }
    // 9 iterations (odd) -> result in bufB[f] (== src after swaps)
    if constexpr (DIR == -1) {
        CT* zr = ztout + (size_t)b * NFFT + (size_t)k2 * 512;
        for (int r = 0; r < L / T; ++r) {
            int k1 = tl + r * T;
            int k  = k1 * 256 + k2;
            double hm = (k == 0 || k == 65536) ? 1.0 : (k < 65536 ? 2.0 : 0.0);
            double2 v = src[k1];
            CT o;
            o.x = (decltype(o.x))(v.x * hm);
            o.y = (decltype(o.y))(v.y * hm);
            zr[k1] = o;
        }
    } else {
        float* er = envout + (size_t)b * NFFT;
        for (int r = 0; r < L / T; ++r) {
            int c1 = tl + r * T;
            double2 v = src[c1];
            er[c1 * 256 + k2] = (float)(sqrt(v.x * v.x + v.y * v.y) * (1.0 / 131072.0));
        }
    }
}

// ================= gradient + 21-tap gaussian smoothing =================
__global__ __launch_bounds__(256) void grad_smooth(const float* __restrict__ env,
                                                   float* __restrict__ sm) {
    __shared__ float  e[280];
    __shared__ double w[21];
    const int b  = blockIdx.y;
    const int n0 = blockIdx.x * 256;
    const float* er = env + (size_t)b * NFFT;
    if (threadIdx.x == 0) {
        double sig = 19.0 / 6.0;
        double tmp[21], sum = 0.0;
        for (int j = 0; j < 21; ++j) {
            double d = (double)(j - 10) / sig;
            tmp[j] = exp(-0.5 * (d * d));
            sum += tmp[j];
        }
        for (int j = 0; j < 21; ++j) w[j] = tmp[j] / sum;
    }
    for (int i = threadIdx.x; i < 278; i += 256) {
        int q = n0 - 11 + i;
        e[i] = er[min(max(q, 0), NFFT - 1)];
    }
    __syncthreads();
    int n = n0 + (int)threadIdx.x;
    double acc = 0.0;
#pragma unroll
    for (int d = -10; d <= 10; ++d) {
        int q = n + d;
        double g;
        if (q < 0 || q > NFFT - 1) {
            g = 0.0;                                   // conv zero-padding of grad
        } else {
            int li = q - (n0 - 11);
            if (q == 0)              g = ((double)e[li + 1] - (double)e[li])     / 10.0;
            else if (q == NFFT - 1)  g = ((double)e[li]     - (double)e[li - 1]) / 10.0;
            else                     g = ((double)e[li + 1] - (double)e[li - 1]) / 20.0;
        }
        acc += w[d + 10] * g;
    }
    sm[(size_t)b * NFFT + n] = (float)acc;
}

// ================= rising-edge bitmasks (f32 compare == reference promotion) =====
__global__ __launch_bounds__(256) void edge_bits(const float* __restrict__ sm,
                                                 unsigned long long* __restrict__ pebits,
                                                 unsigned long long* __restrict__ mebits) {
    const int b = blockIdx.y;
    const int m = blockIdx.x * 256 + threadIdx.x;
    const float* g = sm + (size_t)b * NFFT;
    bool pe = false, me = false;
    if (m < PLEN) {
        float g0 = g[m], g1 = g[m + 1];
        pe = (g1 >  0.01f)   && !(g0 >  0.01f);
        me = (g1 < -0.0025f) && !(g0 < -0.0025f);
    }
    unsigned long long pw = __ballot(pe);
    unsigned long long mw = __ballot(me);
    if ((threadIdx.x & 63) == 0) {
        int wi = m >> 6;
        pebits[b * NWORDS + wi] = pw;
        mebits[b * NWORDS + wi] = mw;
    }
}

// ================= match minus edges to nearest preceding plus edge =============
__global__ __launch_bounds__(256) void match_edges(const unsigned long long* __restrict__ pebits,
                                                   const unsigned long long* __restrict__ mebits,
                                                   int* __restrict__ cand_m,
                                                   int* __restrict__ cand_ap,
                                                   int* __restrict__ cnt,
                                                   int* __restrict__ firstm) {
    int gid = blockIdx.x * 256 + threadIdx.x;         // 65536 = 32 rows * 2048 words
    int b = gid >> 11, w = gid & (NWORDS - 1);
    unsigned long long mw = mebits[b * NWORDS + w];
    const unsigned long long* pb = pebits + b * NWORDS;
    while (mw) {
        int bit = __ffsll(mw) - 1;
        mw &= mw - 1;
        int m = w * 64 + bit;
        int lowpos = m - 599;                          // gap<600 -> p >= m-599
        int p = -1;
        int wi = w;
        unsigned long long pw = pb[wi] & ((bit == 63) ? ~0ull : ((1ull << (bit + 1)) - 1ull));
        while (true) {
            if (pw) { p = wi * 64 + 63 - __clzll(pw); break; }
            --wi;
            if (wi < 0 || wi * 64 + 63 < lowpos) break;
            pw = pb[wi];
        }
        if (p >= 0) {
            int gap = m - p;
            if (gap > 12 && gap < 600) {
                int idx = atomicAdd(&cnt[b], 1);
                if (idx < CAPC) {
                    cand_m [b * CAPC + idx] = m;
                    cand_ap[b * CAPC + idx] = p;
                    atomicMin(&firstm[(size_t)b * NFFT + p], m);
                }
            }
        }
    }
}

// ================= dedup (first minus per plus) -> sort keys =================
__global__ __launch_bounds__(256) void dedup_kept(const int* __restrict__ cand_m,
                                                  const int* __restrict__ cand_ap,
                                                  const int* __restrict__ cnt,
                                                  const int* __restrict__ firstm,
                                                  const float* __restrict__ env,
                                                  unsigned long long* __restrict__ keys,
                                                  int* __restrict__ kcnt) {
    const int b = blockIdx.y;
    const int i = blockIdx.x * 256 + threadIdx.x;
    int n = min(cnt[b], CAPC);
    if (i >= n) return;
    int m  = cand_m [b * CAPC + i];
    int ap = cand_ap[b * CAPC + i];
    if (firstm[(size_t)b * NFFT + ap] == m) {
        float amp = env[(size_t)b * NFFT + m];
        unsigned int ab = __float_as_uint(amp);        // amp >= 0
        unsigned long long key = ((unsigned long long)(~ab) << 32) | (unsigned int)m;
        int j = atomicAdd(&kcnt[b], 1);
        if (j < CAPC) keys[(size_t)b * CAPC + j] = key;
    }
}

// ================= tier-1 selection: top-32 of each 1024-chunk =================
__global__ __launch_bounds__(256) void select1(const unsigned long long* __restrict__ keys,
                                               const int* __restrict__ kcnt,
                                               unsigned long long* __restrict__ finalists) {
    __shared__ unsigned long long sk[1024];
    const int b = blockIdx.y, ch = blockIdx.x;
    int n = min(kcnt[b], CAPC);
    for (int r = 0; r < 4; ++r) {
        int i = r * 256 + threadIdx.x;
        int slot = ch * 1024 + i;
        sk[i] = (slot < n) ? keys[(size_t)b * CAPC + slot] : ~0ull;
    }
    __syncthreads();
    for (int size = 2; size <= 1024; size <<= 1) {
        for (int stride = size >> 1; stride > 0; stride >>= 1) {
            for (int r = 0; r < 4; ++r) {
                int i = r * 256 + threadIdx.x;
                int j = i ^ stride;
                if (j > i) {
                    bool up = ((i & size) == 0);
                    unsigned long long a = sk[i], c = sk[j];
                    if ((a > c) == up) { sk[i] = c; sk[j] = a; }
                }
            }
            __syncthreads();
        }
    }
    if (threadIdx.x < 32)
        finalists[((size_t)b * 16 + ch) * 32 + threadIdx.x] = sk[threadIdx.x];
}

// ================= tier-2: merge 16*32 finalists, output row =================
__global__ __launch_bounds__(256) void select2(const unsigned long long* __restrict__ finalists,
                                               float* __restrict__ out) {
    __shared__ unsigned long long sk[512];
    const int b = blockIdx.x;
    for (int r = 0; r < 2; ++r) {
        int i = r * 256 + threadIdx.x;
        sk[i] = finalists[(size_t)b * 512 + i];
    }
    __syncthreads();
    for (int size = 2; size <= 512; size <<= 1) {
        for (int stride = size >> 1; stride > 0; stride >>= 1) {
            for (int r = 0; r < 2; ++r) {
                int i = r * 256 + threadIdx.x;
                int j = i ^ stride;
                if (j > i) {
                    bool up = ((i & size) == 0);
                    unsigned long long a = sk[i], c = sk[j];
                    if ((a > c) == up) { sk[i] = c; sk[j] = a; }
                }
            }
            __syncthreads();
        }
    }
    if (threadIdx.x == 0) {
        int tmp[32];
        int nsel = 0;
        for (int i = 0; i < 32; ++i)
            if (sk[i] != ~0ull) tmp[nsel++] = (int)(unsigned int)(sk[i] & 0xffffffffu);
        for (int a = 1; a < nsel; ++a) {               // sort ascending by index
            int v = tmp[a], c = a - 1;
            while (c >= 0 && tmp[c] > v) { tmp[c + 1] = tmp[c]; --c; }
            tmp[c + 1] = v;
        }
        for (int s = 0; s < 32; ++s)
            out[b * 32 + s] = (s < 32 - nsel) ? 0.0f : (float)tmp[s - (32 - nsel)];
    }
}

// =========================== launch ===========================
extern "C" void kernel_launch(void* const* d_in, const int* in_sizes, int n_in,
                              void* d_out, int out_size, void* d_ws, size_t ws_size,
                              hipStream_t stream) {
    const float* x = (const float*)d_in[0];
    float* out = (float*)d_out;
    char* ws = (char*)d_ws;

    const size_t TWB = 2097152;                        // 131072 * 16 bytes
    const size_t S_F = 33554432;                       // float2[32][131072]
    const size_t S_D = 67108864;                       // double2[32][131072]
    bool dbl = ws_size >= TWB + 2 * S_D;
    size_t S = dbl ? S_D : S_F;
    if (ws_size < TWB + 2 * S_F) {                     // workspace too small: bail cleanly
        zero_out<<<(out_size + 255) / 256, 256, 0, stream>>>(out, out_size);
        return;
    }

    double2* tw = (double2*)ws;
    char* A  = ws + TWB;                               // Y, then Y2, then misc
    char* Bz = A + S;                                  // Zt, then env+sm
    float* env = (float*)Bz;
    float* sm  = (float*)(Bz + 16777216);
    // misc region (inside A, alive only after inverse pass 2):
    int* firstm = (int*)A;                                                  // 16 MB
    unsigned long long* pebits = (unsigned long long*)(A + 16777216);       // 512 KB
    unsigned long long* mebits = (unsigned long long*)(A + 16777216 + 524288);
    int* cand_m  = (int*)(A + 17825792);                                    // 2 MB
    int* cand_ap = (int*)(A + 19922944);                                    // 2 MB
    unsigned long long* keys      = (unsigned long long*)(A + 22020096);    // 4 MB
    unsigned long long* finalists = (unsigned long long*)(A + 26214400);    // 128 KB
    int* cnt  = (int*)(A + 27262976);                                       // 32 ints
    int* kcnt = cnt + 32;

    setup_tw<<<512, 256, 0, stream>>>(tw);

    dim3 g1(128, BROWS), g2(128, BROWS), blk(256);
    if (dbl) {
        fft_pass1<-1, double2><<<g1, blk, 0, stream>>>(x, (const double2*)nullptr, (double2*)A, tw);
        fft_pass2<-1, double2><<<g2, blk, 0, stream>>>((const double2*)A, (double2*)Bz, (float*)nullptr, tw);
        fft_pass1<+1, double2><<<g1, blk, 0, stream>>>((const float*)nullptr, (const double2*)Bz, (double2*)A, tw);
        fft_pass2<+1, double2><<<g2, blk, 0, stream>>>((const double2*)A, (double2*)nullptr, env, tw);
    } else {
        fft_pass1<-1, float2><<<g1, blk, 0, stream>>>(x, (const float2*)nullptr, (float2*)A, tw);
        fft_pass2<-1, float2><<<g2, blk, 0, stream>>>((const float2*)A, (float2*)Bz, (float*)nullptr, tw);
        fft_pass1<+1, float2><<<g1, blk, 0, stream>>>((const float*)nullptr, (const float2*)Bz, (float2*)A, tw);
        fft_pass2<+1, float2><<<g2, blk, 0, stream>>>((const float2*)A, (float2*)nullptr, env, tw);
    }

    grad_smooth<<<dim3(512, BROWS), blk, 0, stream>>>(env, sm);

    init_scratch<<<16384, 256, 0, stream>>>(firstm, cnt);   // firstm sentinel + cnt/kcnt

    edge_bits  <<<dim3(512, BROWS), blk, 0, stream>>>(sm, pebits, mebits);
    match_edges<<<256, blk, 0, stream>>>(pebits, mebits, cand_m, cand_ap, cnt, firstm);
    dedup_kept <<<dim3(64, BROWS), blk, 0, stream>>>(cand_m, cand_ap, cnt, firstm, env, keys, kcnt);
    select1    <<<dim3(16, BROWS), blk, 0, stream>>>(keys, kcnt, finalists);
    select2    <<<BROWS, blk, 0, stream>>>(finalists, out);
}

// Round 8
// 423.643 us; speedup vs baseline: 3.4562x; 3.4562x over previous
//
#include <hip/hip_runtime.h>
#include <cstdint>

// ---------------- constants ----------------
#define NFFT   131072
#define BROWS  32
#define PLEN   131071
#define NWORDS 2048       // 64-bit words per row of edge bits
#define CAPC   16384      // candidate / kept capacity per row
#define CSTR   32         // counter stride in ints (128 B) -> one cache line per row

// ================= twiddle table: tw[t] = (cos, sin)(2*pi*t/N) =================
__global__ __launch_bounds__(256) void setup_tw(double2* __restrict__ tw) {
    int t = blockIdx.x * 256 + threadIdx.x;           // [0, 131072)
    double ang = 6.283185307179586476925286766559 * ((double)t / 131072.0);
    double s, c;
    sincos(ang, &s, &c);
    tw[t] = make_double2(c, s);
}

// ================= scratch init (capture-safe, replaces hipMemsetAsync) =========
__global__ __launch_bounds__(256) void init_scratch(int* __restrict__ firstm,
                                                    int* __restrict__ cnt) {
    int i = blockIdx.x * 256 + threadIdx.x;           // 4,194,304 ints
    firstm[i] = 0x7F7F7F7F;                           // BIG sentinel for scatter-min
    if (i < 2 * BROWS * CSTR) cnt[i] = 0;             // cnt[32*CSTR] + kcnt[32*CSTR]
}

__global__ __launch_bounds__(256) void zero_out(float* __restrict__ out, int n) {
    int i = blockIdx.x * 256 + threadIdx.x;
    if (i < n) out[i] = 0.0f;
}

// ================= FFT pass 1: 256-pt strided + inter-pass twiddle ==============
// Four-step N = 512*256, n = n2*512 + n1.  Inner DFT over n2 (len 256) for each
// column n1, multiply W_N^{DIR*n1*k2}, store Y[k2*512 + n1].
// DIR = -1: forward, real input x.   DIR = +1: inverse, complex input Zt where
// Zt[k2*512+k1] holds Z[k1*256+k2]  (so Z[m2*512+m1] = Zt[(m1&255)*512 + 2*m2 + (m1>>8)]).
template<int DIR, typename CT>
__global__ __launch_bounds__(256) void fft_pass1(const float* __restrict__ xin,
                                                 const CT* __restrict__ zin,
                                                 CT* __restrict__ yout,
                                                 const double2* __restrict__ tw) {
    constexpr int L = 256, FPB = 4, T = 64, LH = 128;
    __shared__ double2 bufA[FPB][L];
    __shared__ double2 bufB[FPB][L];
    __shared__ double2 twL[255];
    const int b   = blockIdx.y;
    const int f   = threadIdx.x >> 6;
    const int tl  = threadIdx.x & 63;
    const int col = blockIdx.x * FPB + f;             // n1 / m1 in [0,512)

    if (threadIdx.x < 255) {                          // stage twiddles: twL[Ns-1+js]
        int ip = threadIdx.x + 1;
        int s  = 31 - __clz(ip);
        int js = ip - (1 << s);
        twL[threadIdx.x] = tw[js << (16 - s)];        // angle = pi*js/Ns
    }
    if constexpr (DIR == -1) {
        const float* xr = xin + (size_t)b * NFFT;
        for (int r = 0; r < L / T; ++r) {
            int n2 = tl + r * T;
            bufA[f][n2] = make_double2((double)xr[n2 * 512 + col], 0.0);
        }
    } else {
        const CT* zr = zin + (size_t)b * NFFT;
        int c1l = col & 255, c1h = col >> 8;
        for (int r = 0; r < L / T; ++r) {
            int m2 = tl + r * T;
            CT v = zr[c1l * 512 + 2 * m2 + c1h];
            bufA[f][m2] = make_double2((double)v.x, (double)v.y);
        }
    }
    __syncthreads();

    double2* src = bufA[f];
    double2* dst = bufB[f];
    int Ns = 1;
#pragma unroll
    for (int it = 0; it < 8; ++it) {
#pragma unroll
        for (int jj = 0; jj < LH / T; ++jj) {
            int j  = tl + jj * T;
            int js = j & (Ns - 1);
            double2 w = twL[Ns - 1 + js];
            double ws_ = (DIR < 0) ? -w.y : w.y;
            double2 v0 = src[j];
            double2 v1 = src[j + LH];
            double wr = v1.x * w.x - v1.y * ws_;
            double wi = v1.x * ws_ + v1.y * w.x;
            int idxD = ((j - js) << 1) + js;
            dst[idxD]      = make_double2(v0.x + wr, v0.y + wi);
            dst[idxD + Ns] = make_double2(v0.x - wr, v0.y - wi);
        }
        __syncthreads();
        double2* t2 = src; src = dst; dst = t2;
        Ns <<= 1;
    }
    // 8 iterations -> result back in bufA[f] (== src)
    CT* yr = yout + (size_t)b * NFFT;
    for (int r = 0; r < L / T; ++r) {
        int k2 = tl + r * T;
        int t  = (col * k2) & (NFFT - 1);
        double2 w = tw[t];
        double ws_ = (DIR < 0) ? -w.y : w.y;
        double2 v = src[k2];
        CT o;
        o.x = (decltype(o.x))(v.x * w.x - v.y * ws_);
        o.y = (decltype(o.y))(v.x * ws_ + v.y * w.x);
        yr[k2 * 512 + col] = o;
    }
}

// ================= FFT pass 2: 512-pt contiguous ==============
// DIR=-1: apply analytic-filter h(k), write Zt[k2*512+k1].
// DIR=+1: write env[c1*256+c2] = |a|/N (float).
template<int DIR, typename CT>
__global__ __launch_bounds__(256) void fft_pass2(const CT* __restrict__ yin,
                                                 CT* __restrict__ ztout,
                                                 float* __restrict__ envout,
                                                 const double2* __restrict__ tw) {
    constexpr int L = 512, FPB = 2, T = 128, LH = 256;
    __shared__ double2 bufA[FPB][L];
    __shared__ double2 bufB[FPB][L];
    __shared__ double2 twL[511];
    const int b  = blockIdx.y;
    const int f  = threadIdx.x >> 7;
    const int tl = threadIdx.x & 127;
    const int k2 = blockIdx.x * FPB + f;              // [0,256)

    for (int i = threadIdx.x; i < 511; i += 256) {
        int ip = i + 1;
        int s  = 31 - __clz(ip);
        int js = ip - (1 << s);
        twL[i] = tw[js << (16 - s)];
    }
    const CT* yr = yin + (size_t)b * NFFT + (size_t)k2 * 512;
    for (int r = 0; r < L / T; ++r) {
        int i = tl + r * T;
        CT v = yr[i];
        bufA[f][i] = make_double2((double)v.x, (double)v.y);
    }
    __syncthreads();

    double2* src = bufA[f];
    double2* dst = bufB[f];
    int Ns = 1;
#pragma unroll
    for (int it = 0; it < 9; ++it) {
#pragma unroll
        for (int jj = 0; jj < LH / T; ++jj) {
            int j  = tl + jj * T;
            int js = j & (Ns - 1);
            double2 w = twL[Ns - 1 + js];
            double ws_ = (DIR < 0) ? -w.y : w.y;
            double2 v0 = src[j];
            double2 v1 = src[j + LH];
            double wr = v1.x * w.x - v1.y * ws_;
            double wi = v1.x * ws_ + v1.y * w.x;
            int idxD = ((j - js) << 1) + js;
            dst[idxD]      = make_double2(v0.x + wr, v0.y + wi);
            dst[idxD + Ns] = make_double2(v0.x - wr, v0.y - wi);
        }
        __syncthreads();
        double2* t2 = src; src = dst; dst = t2;
        Ns <<= 1;
    }
    // 9 iterations (odd) -> result in bufB[f] (== src after swaps)
    if constexpr (DIR == -1) {
        CT* zr = ztout + (size_t)b * NFFT + (size_t)k2 * 512;
        for (int r = 0; r < L / T; ++r) {
            int k1 = tl + r * T;
            int k  = k1 * 256 + k2;
            double hm = (k == 0 || k == 65536) ? 1.0 : (k < 65536 ? 2.0 : 0.0);
            double2 v = src[k1];
            CT o;
            o.x = (decltype(o.x))(v.x * hm);
            o.y = (decltype(o.y))(v.y * hm);
            zr[k1] = o;
        }
    } else {
        float* er = envout + (size_t)b * NFFT;
        for (int r = 0; r < L / T; ++r) {
            int c1 = tl + r * T;
            double2 v = src[c1];
            er[c1 * 256 + k2] = (float)(sqrt(v.x * v.x + v.y * v.y) * (1.0 / 131072.0));
        }
    }
}

// ================= gradient + 21-tap gaussian smoothing =================
__global__ __launch_bounds__(256) void grad_smooth(const float* __restrict__ env,
                                                   float* __restrict__ sm) {
    __shared__ float  e[280];
    __shared__ double w[21];
    const int b  = blockIdx.y;
    const int n0 = blockIdx.x * 256;
    const float* er = env + (size_t)b * NFFT;
    if (threadIdx.x == 0) {
        double sig = 19.0 / 6.0;
        double tmp[21], sum = 0.0;
        for (int j = 0; j < 21; ++j) {
            double d = (double)(j - 10) / sig;
            tmp[j] = exp(-0.5 * (d * d));
            sum += tmp[j];
        }
        for (int j = 0; j < 21; ++j) w[j] = tmp[j] / sum;
    }
    for (int i = threadIdx.x; i < 278; i += 256) {
        int q = n0 - 11 + i;
        e[i] = er[min(max(q, 0), NFFT - 1)];
    }
    __syncthreads();
    int n = n0 + (int)threadIdx.x;
    double acc = 0.0;
#pragma unroll
    for (int d = -10; d <= 10; ++d) {
        int q = n + d;
        double g;
        if (q < 0 || q > NFFT - 1) {
            g = 0.0;                                   // conv zero-padding of grad
        } else {
            int li = q - (n0 - 11);
            if (q == 0)              g = ((double)e[li + 1] - (double)e[li])     / 10.0;
            else if (q == NFFT - 1)  g = ((double)e[li]     - (double)e[li - 1]) / 10.0;
            else                     g = ((double)e[li + 1] - (double)e[li - 1]) / 20.0;
        }
        acc += w[d + 10] * g;
    }
    sm[(size_t)b * NFFT + n] = (float)acc;
}

// ================= rising-edge bitmasks (f32 compare == reference promotion) =====
__global__ __launch_bounds__(256) void edge_bits(const float* __restrict__ sm,
                                                 unsigned long long* __restrict__ pebits,
                                                 unsigned long long* __restrict__ mebits) {
    const int b = blockIdx.y;
    const int m = blockIdx.x * 256 + threadIdx.x;
    const float* g = sm + (size_t)b * NFFT;
    bool pe = false, me = false;
    if (m < PLEN) {
        float g0 = g[m], g1 = g[m + 1];
        pe = (g1 >  0.01f)   && !(g0 >  0.01f);
        me = (g1 < -0.0025f) && !(g0 < -0.0025f);
    }
    unsigned long long pw = __ballot(pe);
    unsigned long long mw = __ballot(me);
    if ((threadIdx.x & 63) == 0) {
        int wi = m >> 6;
        pebits[b * NWORDS + wi] = pw;
        mebits[b * NWORDS + wi] = mw;
    }
}

// ======= backward scan: nearest plus edge at position <= m, window-limited =======
__device__ __forceinline__ int find_plus(const unsigned long long* __restrict__ pb,
                                         int w, int bit, int m) {
    int lowpos = m - 599;                              // gap<600 -> p >= m-599
    int wi = w;
    unsigned long long pw = pb[wi] & ((bit == 63) ? ~0ull : ((1ull << (bit + 1)) - 1ull));
    while (true) {
        if (pw) return wi * 64 + 63 - __clzll(pw);
        --wi;
        if (wi < 0 || wi * 64 + 63 < lowpos) return -1;
        pw = pb[wi];
    }
}

// ================= match minus edges to nearest preceding plus edge =============
// Wave-aggregated compaction: per-candidate atomicAdd on a shared counter line was
// ~1 ms of hot-line serialization (round-4 profile: 1031 us, VALUBusy 0.057%).
// Now: count -> wave prefix-sum -> ONE atomicAdd per wave -> re-scan and write.
__global__ __launch_bounds__(256) void match_edges(const unsigned long long* __restrict__ pebits,
                                                   const unsigned long long* __restrict__ mebits,
                                                   int* __restrict__ cand_m,
                                                   int* __restrict__ cand_ap,
                                                   int* __restrict__ cnt,
                                                   int* __restrict__ firstm) {
    int gid = blockIdx.x * 256 + threadIdx.x;         // 65536 = 32 rows * 2048 words
    int b = gid >> 11, w = gid & (NWORDS - 1);        // wave never straddles rows (64|2048)
    int lane = threadIdx.x & 63;
    const unsigned long long mw0 = mebits[b * NWORDS + w];
    const unsigned long long* pb = pebits + b * NWORDS;

    // pass A: count valid candidates in this word
    int myc = 0;
    unsigned long long mw = mw0;
    while (mw) {
        int bit = __ffsll(mw) - 1;
        mw &= mw - 1;
        int m = w * 64 + bit;
        int p = find_plus(pb, w, bit, m);
        if (p >= 0) {
            int gap = m - p;
            if (gap > 12 && gap < 600) ++myc;
        }
    }

    // inclusive wave-wide prefix sum of myc
    int scan = myc;
#pragma unroll
    for (int off = 1; off < 64; off <<= 1) {
        int v = __shfl_up(scan, off, 64);
        if (lane >= off) scan += v;
    }
    int total = __shfl(scan, 63, 64);
    int base = 0;
    if (total > 0) {
        if (lane == 63) base = atomicAdd(&cnt[b * CSTR], total);
        base = __shfl(base, 63, 64);
    }
    int idx = base + scan - myc;                      // this thread's exclusive offset

    // pass B: re-scan, write candidates, scatter-min for dedup
    mw = mw0;
    while (mw) {
        int bit = __ffsll(mw) - 1;
        mw &= mw - 1;
        int m = w * 64 + bit;
        int p = find_plus(pb, w, bit, m);
        if (p >= 0) {
            int gap = m - p;
            if (gap > 12 && gap < 600) {
                if (idx < CAPC) {
                    cand_m [b * CAPC + idx] = m;
                    cand_ap[b * CAPC + idx] = p;
                    atomicMin(&firstm[(size_t)b * NFFT + p], m);   // fire-and-forget
                }
                ++idx;
            }
        }
    }
}

// ================= dedup (first minus per plus) -> sort keys =================
// Ballot-aggregated: one atomicAdd per wave instead of one per kept entry.
__global__ __launch_bounds__(256) void dedup_kept(const int* __restrict__ cand_m,
                                                  const int* __restrict__ cand_ap,
                                                  const int* __restrict__ cnt,
                                                  const int* __restrict__ firstm,
                                                  const float* __restrict__ env,
                                                  unsigned long long* __restrict__ keys,
                                                  int* __restrict__ kcnt) {
    const int b = blockIdx.y;
    const int i = blockIdx.x * 256 + threadIdx.x;
    const int lane = threadIdx.x & 63;
    int n = min(cnt[b * CSTR], CAPC);

    bool kept = false;
    unsigned long long key = 0;
    if (i < n) {
        int m  = cand_m [b * CAPC + i];
        int ap = cand_ap[b * CAPC + i];
        if (firstm[(size_t)b * NFFT + ap] == m) {
            float amp = env[(size_t)b * NFFT + m];
            unsigned int ab = __float_as_uint(amp);    // amp >= 0
            key = ((unsigned long long)(~ab) << 32) | (unsigned int)m;
            kept = true;
        }
    }
    unsigned long long bal = __ballot(kept);
    int tot = __popcll(bal);
    if (tot > 0) {
        int base = 0;
        if (lane == 0) base = atomicAdd(&kcnt[b * CSTR], tot);
        base = __shfl(base, 0, 64);
        if (kept) {
            int off = __popcll(bal & ((lane == 0) ? 0ull : ((1ull << lane) - 1ull)));
            int j = base + off;
            if (j < CAPC) keys[(size_t)b * CAPC + j] = key;
        }
    }
}

// ================= tier-1 selection: top-32 of each 1024-chunk =================
__global__ __launch_bounds__(256) void select1(const unsigned long long* __restrict__ keys,
                                               const int* __restrict__ kcnt,
                                               unsigned long long* __restrict__ finalists) {
    __shared__ unsigned long long sk[1024];
    const int b = blockIdx.y, ch = blockIdx.x;
    int n = min(kcnt[b * CSTR], CAPC);
    for (int r = 0; r < 4; ++r) {
        int i = r * 256 + threadIdx.x;
        int slot = ch * 1024 + i;
        sk[i] = (slot < n) ? keys[(size_t)b * CAPC + slot] : ~0ull;
    }
    __syncthreads();
    for (int size = 2; size <= 1024; size <<= 1) {
        for (int stride = size >> 1; stride > 0; stride >>= 1) {
            for (int r = 0; r < 4; ++r) {
                int i = r * 256 + threadIdx.x;
                int j = i ^ stride;
                if (j > i) {
                    bool up = ((i & size) == 0);
                    unsigned long long a = sk[i], c = sk[j];
                    if ((a > c) == up) { sk[i] = c; sk[j] = a; }
                }
            }
            __syncthreads();
        }
    }
    if (threadIdx.x < 32)
        finalists[((size_t)b * 16 + ch) * 32 + threadIdx.x] = sk[threadIdx.x];
}

// ================= tier-2: merge 16*32 finalists, output row =================
__global__ __launch_bounds__(256) void select2(const unsigned long long* __restrict__ finalists,
                                               float* __restrict__ out) {
    __shared__ unsigned long long sk[512];
    const int b = blockIdx.x;
    for (int r = 0; r < 2; ++r) {
        int i = r * 256 + threadIdx.x;
        sk[i] = finalists[(size_t)b * 512 + i];
    }
    __syncthreads();
    for (int size = 2; size <= 512; size <<= 1) {
        for (int stride = size >> 1; stride > 0; stride >>= 1) {
            for (int r = 0; r < 2; ++r) {
                int i = r * 256 + threadIdx.x;
                int j = i ^ stride;
                if (j > i) {
                    bool up = ((i & size) == 0);
                    unsigned long long a = sk[i], c = sk[j];
                    if ((a > c) == up) { sk[i] = c; sk[j] = a; }
                }
            }
            __syncthreads();
        }
    }
    if (threadIdx.x == 0) {
        int tmp[32];
        int nsel = 0;
        for (int i = 0; i < 32; ++i)
            if (sk[i] != ~0ull) tmp[nsel++] = (int)(unsigned int)(sk[i] & 0xffffffffu);
        for (int a = 1; a < nsel; ++a) {               // sort ascending by index
            int v = tmp[a], c = a - 1;
            while (c >= 0 && tmp[c] > v) { tmp[c + 1] = tmp[c]; --c; }
            tmp[c + 1] = v;
        }
        for (int s = 0; s < 32; ++s)
            out[b * 32 + s] = (s < 32 - nsel) ? 0.0f : (float)tmp[s - (32 - nsel)];
    }
}

// =========================== launch ===========================
extern "C" void kernel_launch(void* const* d_in, const int* in_sizes, int n_in,
                              void* d_out, int out_size, void* d_ws, size_t ws_size,
                              hipStream_t stream) {
    const float* x = (const float*)d_in[0];
    float* out = (float*)d_out;
    char* ws = (char*)d_ws;

    const size_t TWB = 2097152;                        // 131072 * 16 bytes
    const size_t S_F = 33554432;                       // float2[32][131072]
    const size_t S_D = 67108864;                       // double2[32][131072]
    bool dbl = ws_size >= TWB + 2 * S_D;
    size_t S = dbl ? S_D : S_F;
    if (ws_size < TWB + 2 * S_F) {                     // workspace too small: bail cleanly
        zero_out<<<(out_size + 255) / 256, 256, 0, stream>>>(out, out_size);
        return;
    }

    double2* tw = (double2*)ws;
    char* A  = ws + TWB;                               // Y, then Y2, then misc
    char* Bz = A + S;                                  // Zt, then env+sm
    float* env = (float*)Bz;
    float* sm  = (float*)(Bz + 16777216);
    // misc region (inside A, alive only after inverse pass 2):
    int* firstm = (int*)A;                                                  // 16 MB
    unsigned long long* pebits = (unsigned long long*)(A + 16777216);       // 512 KB
    unsigned long long* mebits = (unsigned long long*)(A + 16777216 + 524288);
    int* cand_m  = (int*)(A + 17825792);                                    // 2 MB
    int* cand_ap = (int*)(A + 19922944);                                    // 2 MB
    unsigned long long* keys      = (unsigned long long*)(A + 22020096);    // 4 MB
    unsigned long long* finalists = (unsigned long long*)(A + 26214400);    // 128 KB
    int* cnt  = (int*)(A + 27262976);                  // 32*CSTR ints (1 line per row)
    int* kcnt = cnt + BROWS * CSTR;                    // 32*CSTR ints

    setup_tw<<<512, 256, 0, stream>>>(tw);

    dim3 g1(128, BROWS), g2(128, BROWS), blk(256);
    if (dbl) {
        fft_pass1<-1, double2><<<g1, blk, 0, stream>>>(x, (const double2*)nullptr, (double2*)A, tw);
        fft_pass2<-1, double2><<<g2, blk, 0, stream>>>((const double2*)A, (double2*)Bz, (float*)nullptr, tw);
        fft_pass1<+1, double2><<<g1, blk, 0, stream>>>((const float*)nullptr, (const double2*)Bz, (double2*)A, tw);
        fft_pass2<+1, double2><<<g2, blk, 0, stream>>>((const double2*)A, (double2*)nullptr, env, tw);
    } else {
        fft_pass1<-1, float2><<<g1, blk, 0, stream>>>(x, (const float2*)nullptr, (float2*)A, tw);
        fft_pass2<-1, float2><<<g2, blk, 0, stream>>>((const float2*)A, (float2*)Bz, (float*)nullptr, tw);
        fft_pass1<+1, float2><<<g1, blk, 0, stream>>>((const float*)nullptr, (const float2*)Bz, (float2*)A, tw);
        fft_pass2<+1, float2><<<g2, blk, 0, stream>>>((const float2*)A, (float2*)nullptr, env, tw);
    }

    grad_smooth<<<dim3(512, BROWS), blk, 0, stream>>>(env, sm);

    init_scratch<<<16384, 256, 0, stream>>>(firstm, cnt);   // firstm sentinel + cnt/kcnt

    edge_bits  <<<dim3(512, BROWS), blk, 0, stream>>>(sm, pebits, mebits);
    match_edges<<<256, blk, 0, stream>>>(pebits, mebits, cand_m, cand_ap, cnt, firstm);
    dedup_kept <<<dim3(64, BROWS), blk, 0, stream>>>(cand_m, cand_ap, cnt, firstm, env, keys, kcnt);
    select1    <<<dim3(16, BROWS), blk, 0, stream>>>(keys, kcnt, finalists);
    select2    <<<BROWS, blk, 0, stream>>>(finalists, out);
}

// Round 10
// 341.145 us; speedup vs baseline: 4.2920x; 1.2418x over previous
//
#include <hip/hip_runtime.h>
#include <cstdint>

// ---------------- constants ----------------
#define NFFT   131072
#define BROWS  32
#define PLEN   131071
#define NWORDS 2048       // 64-bit words per row of edge bits
#define CAPC   16384      // candidate / kept capacity per row
#define CSTR   32         // counter stride in ints (128 B) -> one cache line per row

// ================= twiddle table: tw[t] = (cos, sin)(2*pi*t/N) =================
// Symmetry: tw[t + N/2] = -tw[t] (exact negation) -> half the sincos calls.
__global__ __launch_bounds__(256) void setup_tw(double2* __restrict__ tw) {
    int t = blockIdx.x * 256 + threadIdx.x;           // [0, 65536)
    double ang = 6.283185307179586476925286766559 * ((double)t / 131072.0);
    double s, c;
    sincos(ang, &s, &c);
    tw[t] = make_double2(c, s);
    tw[t + 65536] = make_double2(-c, -s);
}

// ================= scratch init + gaussian weights (capture-safe) ===============
// wtab computed ONCE here (parallel exp, same summation order as before) instead
// of per-block serial exp in grad_smooth (round-8 profile: 86.7 us, VALUBusy 67%).
__global__ __launch_bounds__(256) void init_scratch(int* __restrict__ firstm,
                                                    int* __restrict__ cnt,
                                                    double* __restrict__ wtab) {
    __shared__ double tmp[21];
    int i = blockIdx.x * 256 + threadIdx.x;           // 4,194,304 ints
    firstm[i] = 0x7F7F7F7F;                           // BIG sentinel for scatter-min
    if (i < 2 * BROWS * CSTR) cnt[i] = 0;             // cnt[32*CSTR] + kcnt[32*CSTR]
    if (blockIdx.x == 0) {
        if (threadIdx.x < 21) {
            double sig = 19.0 / 6.0;
            double d = (double)((int)threadIdx.x - 10) / sig;
            tmp[threadIdx.x] = exp(-0.5 * (d * d));
        }
        __syncthreads();
        if (threadIdx.x < 21) {
            double s = 0.0;
            for (int j = 0; j < 21; ++j) s += tmp[j]; // same order as reference loop
            wtab[threadIdx.x] = tmp[threadIdx.x] / s;
        }
    }
}

__global__ __launch_bounds__(256) void zero_out(float* __restrict__ out, int n) {
    int i = blockIdx.x * 256 + threadIdx.x;
    if (i < n) out[i] = 0.0f;
}

// ================= FFT pass 1: 256-pt strided + inter-pass twiddle ==============
// Four-step N = 512*256, n = n2*512 + n1.  Inner DFT over n2 (len 256) for each
// column n1, multiply W_N^{DIR*n1*k2}, store Y[k2*512 + n1].
// DIR = -1: forward, real input x.   DIR = +1: inverse, complex input Zt where
// Zt[k2*512+k1] holds Z[k1*256+k2]  (so Z[m2*512+m1] = Zt[(m1&255)*512 + 2*m2 + (m1>>8)]).
// Global I/O is cooperatively re-indexed across the block for coalescing:
//   load (fwd):  thread t <-> (col=t&3, row=t>>2): 16 B/row-segment (was 4 B/line)
//   store (both): 4 consecutive double2 = full 64 B line per 4-lane group (1x amp)
template<int DIR, typename CT>
__global__ __launch_bounds__(256) void fft_pass1(const float* __restrict__ xin,
                                                 const CT* __restrict__ zin,
                                                 CT* __restrict__ yout,
                                                 const double2* __restrict__ tw) {
    constexpr int L = 256, FPB = 4, T = 64, LH = 128;
    __shared__ double2 bufA[FPB][L];
    __shared__ double2 bufB[FPB][L];
    __shared__ double2 twL[255];
    const int b    = blockIdx.y;
    const int f    = threadIdx.x >> 6;
    const int tl   = threadIdx.x & 63;
    const int col0 = blockIdx.x * FPB;
    const int col  = col0 + f;                        // n1 / m1 in [0,512)

    if (threadIdx.x < 255) {                          // stage twiddles: twL[Ns-1+js]
        int ip = threadIdx.x + 1;
        int s  = 31 - __clz(ip);
        int js = ip - (1 << s);
        twL[threadIdx.x] = tw[js << (16 - s)];        // angle = pi*js/Ns
    }
    if constexpr (DIR == -1) {
        // cooperative coalesced load of tile x[0..255][col0..col0+3]
        const float* xr = xin + (size_t)b * NFFT;
        for (int r = 0; r < 4; ++r) {
            int t = (int)threadIdx.x + r * 256;       // [0,1024)
            int c = t & 3, row = t >> 2;
            bufA[c][row] = make_double2((double)xr[row * 512 + col0 + c], 0.0);
        }
    } else {
        // inverse gather: contiguous direction is m2 (stride 2 elems) -> keep fiber map
        const CT* zr = zin + (size_t)b * NFFT;
        int c1l = col & 255, c1h = col >> 8;
        for (int r = 0; r < L / T; ++r) {
            int m2 = tl + r * T;
            CT v = zr[c1l * 512 + 2 * m2 + c1h];
            bufA[f][m2] = make_double2((double)v.x, (double)v.y);
        }
    }
    __syncthreads();

    double2* src = bufA[f];
    double2* dst = bufB[f];
    int Ns = 1;
#pragma unroll
    for (int it = 0; it < 8; ++it) {
#pragma unroll
        for (int jj = 0; jj < LH / T; ++jj) {
            int j  = tl + jj * T;
            int js = j & (Ns - 1);
            double2 w = twL[Ns - 1 + js];
            double ws_ = (DIR < 0) ? -w.y : w.y;
            double2 v0 = src[j];
            double2 v1 = src[j + LH];
            double wr = v1.x * w.x - v1.y * ws_;
            double wi = v1.x * ws_ + v1.y * w.x;
            int idxD = ((j - js) << 1) + js;
            dst[idxD]      = make_double2(v0.x + wr, v0.y + wi);
            dst[idxD + Ns] = make_double2(v0.x - wr, v0.y - wi);
        }
        __syncthreads();
        double2* t2 = src; src = dst; dst = t2;
        Ns <<= 1;
    }
    // 8 iterations -> each fiber's result in bufA[f] (last syncthreads already done)
    // cooperative store: 4-lane groups write 4 consecutive double2 = 64 B lines
    CT* yr = yout + (size_t)b * NFFT;
    for (int r = 0; r < 4; ++r) {
        int t = (int)threadIdx.x + r * 256;           // [0,1024)
        int c = t & 3, k2 = t >> 2;
        int tt = ((col0 + c) * k2) & (NFFT - 1);
        double2 w = tw[tt];
        double ws_ = (DIR < 0) ? -w.y : w.y;
        double2 v = bufA[c][k2];
        CT o;
        o.x = (decltype(o.x))(v.x * w.x - v.y * ws_);
        o.y = (decltype(o.y))(v.x * ws_ + v.y * w.x);
        yr[(size_t)k2 * 512 + col0 + c] = o;
    }
}

// ================= FFT pass 2: 512-pt contiguous ==============
// DIR=-1: apply analytic-filter h(k), write Zt[k2*512+k1].
// DIR=+1: write env[c1*256+c2] = |a|/N (float), float2-coalesced across fibers.
template<int DIR, typename CT>
__global__ __launch_bounds__(256) void fft_pass2(const CT* __restrict__ yin,
                                                 CT* __restrict__ ztout,
                                                 float* __restrict__ envout,
                                                 const double2* __restrict__ tw) {
    constexpr int L = 512, FPB = 2, T = 128, LH = 256;
    __shared__ double2 bufA[FPB][L];
    __shared__ double2 bufB[FPB][L];
    __shared__ double2 twL[511];
    const int b  = blockIdx.y;
    const int f  = threadIdx.x >> 7;
    const int tl = threadIdx.x & 127;
    const int k2 = blockIdx.x * FPB + f;              // [0,256)

    for (int i = threadIdx.x; i < 511; i += 256) {
        int ip = i + 1;
        int s  = 31 - __clz(ip);
        int js = ip - (1 << s);
        twL[i] = tw[js << (16 - s)];
    }
    const CT* yr = yin + (size_t)b * NFFT + (size_t)k2 * 512;
    for (int r = 0; r < L / T; ++r) {
        int i = tl + r * T;
        CT v = yr[i];
        bufA[f][i] = make_double2((double)v.x, (double)v.y);
    }
    __syncthreads();

    double2* src = bufA[f];
    double2* dst = bufB[f];
    int Ns = 1;
#pragma unroll
    for (int it = 0; it < 9; ++it) {
#pragma unroll
        for (int jj = 0; jj < LH / T; ++jj) {
            int j  = tl + jj * T;
            int js = j & (Ns - 1);
            double2 w = twL[Ns - 1 + js];
            double ws_ = (DIR < 0) ? -w.y : w.y;
            double2 v0 = src[j];
            double2 v1 = src[j + LH];
            double wr = v1.x * w.x - v1.y * ws_;
            double wi = v1.x * ws_ + v1.y * w.x;
            int idxD = ((j - js) << 1) + js;
            dst[idxD]      = make_double2(v0.x + wr, v0.y + wi);
            dst[idxD + Ns] = make_double2(v0.x - wr, v0.y - wi);
        }
        __syncthreads();
        double2* t2 = src; src = dst; dst = t2;
        Ns <<= 1;
    }
    // 9 iterations (odd) -> each fiber's result in bufB[f] (already synced)
    if constexpr (DIR == -1) {
        CT* zr = ztout + (size_t)b * NFFT + (size_t)k2 * 512;
        for (int r = 0; r < L / T; ++r) {
            int k1 = tl + r * T;
            int k  = k1 * 256 + k2;
            double hm = (k == 0 || k == 65536) ? 1.0 : (k < 65536 ? 2.0 : 0.0);
            double2 v = src[k1];
            CT o;
            o.x = (decltype(o.x))(v.x * hm);
            o.y = (decltype(o.y))(v.y * hm);
            zr[k1] = o;
        }
    } else {
        float* er = envout + (size_t)b * NFFT;
        int k20 = blockIdx.x * FPB;
        for (int r = 0; r < 2; ++r) {
            int c1 = (int)threadIdx.x + r * 256;      // [0,512)
            double2 v0 = bufB[0][c1];
            double2 v1 = bufB[1][c1];
            float2 o;
            o.x = (float)(sqrt(v0.x * v0.x + v0.y * v0.y) * (1.0 / 131072.0));
            o.y = (float)(sqrt(v1.x * v1.x + v1.y * v1.y) * (1.0 / 131072.0));
            *(float2*)&er[(size_t)c1 * 256 + k20] = o;
        }
    }
}

// ================= gradient + 21-tap gaussian smoothing =================
// Weights from wtab (precomputed once); gradient staged in LDS so the conv is a
// pure 21-tap FMA loop. Same f64 expressions as before -> bit-identical output.
__global__ __launch_bounds__(256) void grad_smooth(const float* __restrict__ env,
                                                   const double* __restrict__ wtab,
                                                   float* __restrict__ sm) {
    __shared__ float  e[280];
    __shared__ double g[278];
    __shared__ double w[21];
    const int b  = blockIdx.y;
    const int n0 = blockIdx.x * 256;
    const float* er = env + (size_t)b * NFFT;
    if (threadIdx.x < 21) w[threadIdx.x] = wtab[threadIdx.x];
    for (int i = threadIdx.x; i < 278; i += 256) {
        int q = n0 - 11 + i;
        e[i] = er[min(max(q, 0), NFFT - 1)];
    }
    __syncthreads();
    // g[i] = torch.gradient-style grad at q = n0-11+i (zero outside [0,N-1]);
    // only i in [1,276] is ever read by the conv below.
    for (int i = threadIdx.x + 1; i < 277; i += 256) {
        int q = n0 - 11 + i;
        double gv;
        if (q < 0 || q > NFFT - 1)   gv = 0.0;
        else if (q == 0)             gv = ((double)e[i + 1] - (double)e[i])     / 10.0;
        else if (q == NFFT - 1)      gv = ((double)e[i]     - (double)e[i - 1]) / 10.0;
        else                         gv = ((double)e[i + 1] - (double)e[i - 1]) / 20.0;
        g[i] = gv;
    }
    __syncthreads();
    double acc = 0.0;
#pragma unroll
    for (int d = 0; d < 21; ++d)
        acc += w[d] * g[threadIdx.x + 1 + d];
    sm[(size_t)b * NFFT + n0 + threadIdx.x] = (float)acc;
}

// ================= rising-edge bitmasks (f32 compare == reference promotion) =====
__global__ __launch_bounds__(256) void edge_bits(const float* __restrict__ sm,
                                                 unsigned long long* __restrict__ pebits,
                                                 unsigned long long* __restrict__ mebits) {
    const int b = blockIdx.y;
    const int m = blockIdx.x * 256 + threadIdx.x;
    const float* g = sm + (size_t)b * NFFT;
    bool pe = false, me = false;
    if (m < PLEN) {
        float g0 = g[m], g1 = g[m + 1];
        pe = (g1 >  0.01f)   && !(g0 >  0.01f);
        me = (g1 < -0.0025f) && !(g0 < -0.0025f);
    }
    unsigned long long pw = __ballot(pe);
    unsigned long long mw = __ballot(me);
    if ((threadIdx.x & 63) == 0) {
        int wi = m >> 6;
        pebits[b * NWORDS + wi] = pw;
        mebits[b * NWORDS + wi] = mw;
    }
}

// ======= backward scan: nearest plus edge at position <= m, window-limited =======
__device__ __forceinline__ int find_plus(const unsigned long long* __restrict__ pb,
                                         int w, int bit, int m) {
    int lowpos = m - 599;                              // gap<600 -> p >= m-599
    int wi = w;
    unsigned long long pw = pb[wi] & ((bit == 63) ? ~0ull : ((1ull << (bit + 1)) - 1ull));
    while (true) {
        if (pw) return wi * 64 + 63 - __clzll(pw);
        --wi;
        if (wi < 0 || wi * 64 + 63 < lowpos) return -1;
        pw = pb[wi];
    }
}

// ================= match minus edges to nearest preceding plus edge =============
// Wave-aggregated compaction: count -> wave prefix-sum -> ONE atomicAdd per wave.
__global__ __launch_bounds__(256) void match_edges(const unsigned long long* __restrict__ pebits,
                                                   const unsigned long long* __restrict__ mebits,
                                                   int* __restrict__ cand_m,
                                                   int* __restrict__ cand_ap,
                                                   int* __restrict__ cnt,
                                                   int* __restrict__ firstm) {
    int gid = blockIdx.x * 256 + threadIdx.x;         // 65536 = 32 rows * 2048 words
    int b = gid >> 11, w = gid & (NWORDS - 1);        // wave never straddles rows (64|2048)
    int lane = threadIdx.x & 63;
    const unsigned long long mw0 = mebits[b * NWORDS + w];
    const unsigned long long* pb = pebits + b * NWORDS;

    // pass A: count valid candidates in this word
    int myc = 0;
    unsigned long long mw = mw0;
    while (mw) {
        int bit = __ffsll(mw) - 1;
        mw &= mw - 1;
        int m = w * 64 + bit;
        int p = find_plus(pb, w, bit, m);
        if (p >= 0) {
            int gap = m - p;
            if (gap > 12 && gap < 600) ++myc;
        }
    }

    // inclusive wave-wide prefix sum of myc
    int scan = myc;
#pragma unroll
    for (int off = 1; off < 64; off <<= 1) {
        int v = __shfl_up(scan, off, 64);
        if (lane >= off) scan += v;
    }
    int total = __shfl(scan, 63, 64);
    int base = 0;
    if (total > 0) {
        if (lane == 63) base = atomicAdd(&cnt[b * CSTR], total);
        base = __shfl(base, 63, 64);
    }
    int idx = base + scan - myc;                      // this thread's exclusive offset

    // pass B: re-scan, write candidates, scatter-min for dedup
    mw = mw0;
    while (mw) {
        int bit = __ffsll(mw) - 1;
        mw &= mw - 1;
        int m = w * 64 + bit;
        int p = find_plus(pb, w, bit, m);
        if (p >= 0) {
            int gap = m - p;
            if (gap > 12 && gap < 600) {
                if (idx < CAPC) {
                    cand_m [b * CAPC + idx] = m;
                    cand_ap[b * CAPC + idx] = p;
                    atomicMin(&firstm[(size_t)b * NFFT + p], m);   // fire-and-forget
                }
                ++idx;
            }
        }
    }
}

// ================= dedup (first minus per plus) -> sort keys =================
// Ballot-aggregated: one atomicAdd per wave instead of one per kept entry.
__global__ __launch_bounds__(256) void dedup_kept(const int* __restrict__ cand_m,
                                                  const int* __restrict__ cand_ap,
                                                  const int* __restrict__ cnt,
                                                  const int* __restrict__ firstm,
                                                  const float* __restrict__ env,
                                                  unsigned long long* __restrict__ keys,
                                                  int* __restrict__ kcnt) {
    const int b = blockIdx.y;
    const int i = blockIdx.x * 256 + threadIdx.x;
    const int lane = threadIdx.x & 63;
    int n = min(cnt[b * CSTR], CAPC);

    bool kept = false;
    unsigned long long key = 0;
    if (i < n) {
        int m  = cand_m [b * CAPC + i];
        int ap = cand_ap[b * CAPC + i];
        if (firstm[(size_t)b * NFFT + ap] == m) {
            float amp = env[(size_t)b * NFFT + m];
            unsigned int ab = __float_as_uint(amp);    // amp >= 0
            key = ((unsigned long long)(~ab) << 32) | (unsigned int)m;
            kept = true;
        }
    }
    unsigned long long bal = __ballot(kept);
    int tot = __popcll(bal);
    if (tot > 0) {
        int base = 0;
        if (lane == 0) base = atomicAdd(&kcnt[b * CSTR], tot);
        base = __shfl(base, 0, 64);
        if (kept) {
            int off = __popcll(bal & ((lane == 0) ? 0ull : ((1ull << lane) - 1ull)));
            int j = base + off;
            if (j < CAPC) keys[(size_t)b * CAPC + j] = key;
        }
    }
}

// ================= tier-1 selection: top-32 of each 1024-chunk =================
__global__ __launch_bounds__(256) void select1(const unsigned long long* __restrict__ keys,
                                               const int* __restrict__ kcnt,
                                               unsigned long long* __restrict__ finalists) {
    __shared__ unsigned long long sk[1024];
    const int b = blockIdx.y, ch = blockIdx.x;
    int n = min(kcnt[b * CSTR], CAPC);
    for (int r = 0; r < 4; ++r) {
        int i = r * 256 + threadIdx.x;
        int slot = ch * 1024 + i;
        sk[i] = (slot < n) ? keys[(size_t)b * CAPC + slot] : ~0ull;
    }
    __syncthreads();
    for (int size = 2; size <= 1024; size <<= 1) {
        for (int stride = size >> 1; stride > 0; stride >>= 1) {
            for (int r = 0; r < 4; ++r) {
                int i = r * 256 + threadIdx.x;
                int j = i ^ stride;
                if (j > i) {
                    bool up = ((i & size) == 0);
                    unsigned long long a = sk[i], c = sk[j];
                    if ((a > c) == up) { sk[i] = c; sk[j] = a; }
                }
            }
            __syncthreads();
        }
    }
    if (threadIdx.x < 32)
        finalists[((size_t)b * 16 + ch) * 32 + threadIdx.x] = sk[threadIdx.x];
}

// ================= tier-2: merge 16*32 finalists, output row =================
__global__ __launch_bounds__(256) void select2(const unsigned long long* __restrict__ finalists,
                                               float* __restrict__ out) {
    __shared__ unsigned long long sk[512];
    const int b = blockIdx.x;
    for (int r = 0; r < 2; ++r) {
        int i = r * 256 + threadIdx.x;
        sk[i] = finalists[(size_t)b * 512 + i];
    }
    __syncthreads();
    for (int size = 2; size <= 512; size <<= 1) {
        for (int stride = size >> 1; stride > 0; stride >>= 1) {
            for (int r = 0; r < 2; ++r) {
                int i = r * 256 + threadIdx.x;
                int j = i ^ stride;
                if (j > i) {
                    bool up = ((i & size) == 0);
                    unsigned long long a = sk[i], c = sk[j];
                    if ((a > c) == up) { sk[i] = c; sk[j] = a; }
                }
            }
            __syncthreads();
        }
    }
    if (threadIdx.x == 0) {
        int tmp[32];
        int nsel = 0;
        for (int i = 0; i < 32; ++i)
            if (sk[i] != ~0ull) tmp[nsel++] = (int)(unsigned int)(sk[i] & 0xffffffffu);
        for (int a = 1; a < nsel; ++a) {               // sort ascending by index
            int v = tmp[a], c = a - 1;
            while (c >= 0 && tmp[c] > v) { tmp[c + 1] = tmp[c]; --c; }
            tmp[c + 1] = v;
        }
        for (int s = 0; s < 32; ++s)
            out[b * 32 + s] = (s < 32 - nsel) ? 0.0f : (float)tmp[s - (32 - nsel)];
    }
}

// =========================== launch ===========================
extern "C" void kernel_launch(void* const* d_in, const int* in_sizes, int n_in,
                              void* d_out, int out_size, void* d_ws, size_t ws_size,
                              hipStream_t stream) {
    const float* x = (const float*)d_in[0];
    float* out = (float*)d_out;
    char* ws = (char*)d_ws;

    const size_t TWB = 2097152;                        // 131072 * 16 bytes
    const size_t S_F = 33554432;                       // float2[32][131072]
    const size_t S_D = 67108864;                       // double2[32][131072]
    bool dbl = ws_size >= TWB + 2 * S_D;
    size_t S = dbl ? S_D : S_F;
    if (ws_size < TWB + 2 * S_F) {                     // workspace too small: bail cleanly
        zero_out<<<(out_size + 255) / 256, 256, 0, stream>>>(out, out_size);
        return;
    }

    double2* tw = (double2*)ws;
    char* A  = ws + TWB;                               // Y, then Y2, then misc
    char* Bz = A + S;                                  // Zt, then env+sm
    float* env = (float*)Bz;
    float* sm  = (float*)(Bz + 16777216);
    // misc region (inside A, alive only after inverse pass 2):
    int* firstm = (int*)A;                                                  // 16 MB
    unsigned long long* pebits = (unsigned long long*)(A + 16777216);       // 512 KB
    unsigned long long* mebits = (unsigned long long*)(A + 16777216 + 524288);
    int* cand_m  = (int*)(A + 17825792);                                    // 2 MB
    int* cand_ap = (int*)(A + 19922944);                                    // 2 MB
    unsigned long long* keys      = (unsigned long long*)(A + 22020096);    // 4 MB
    unsigned long long* finalists = (unsigned long long*)(A + 26214400);    // 128 KB
    int* cnt  = (int*)(A + 27262976);                  // 32*CSTR ints (1 line per row)
    int* kcnt = cnt + BROWS * CSTR;                    // 32*CSTR ints
    double* wtab = (double*)(A + 27271168);            // 21 gaussian weights

    setup_tw<<<256, 256, 0, stream>>>(tw);             // halved via tw[t+N/2] = -tw[t]

    dim3 g1(128, BROWS), g2(128, BROWS), blk(256);
    if (dbl) {
        fft_pass1<-1, double2><<<g1, blk, 0, stream>>>(x, (const double2*)nullptr, (double2*)A, tw);
        fft_pass2<-1, double2><<<g2, blk, 0, stream>>>((const double2*)A, (double2*)Bz, (float*)nullptr, tw);
        fft_pass1<+1, double2><<<g1, blk, 0, stream>>>((const float*)nullptr, (const double2*)Bz, (double2*)A, tw);
        fft_pass2<+1, double2><<<g2, blk, 0, stream>>>((const double2*)A, (double2*)nullptr, env, tw);
    } else {
        fft_pass1<-1, float2><<<g1, blk, 0, stream>>>(x, (const float2*)nullptr, (float2*)A, tw);
        fft_pass2<-1, float2><<<g2, blk, 0, stream>>>((const float2*)A, (float2*)Bz, (float*)nullptr, tw);
        fft_pass1<+1, float2><<<g1, blk, 0, stream>>>((const float*)nullptr, (const float2*)Bz, (float2*)A, tw);
        fft_pass2<+1, float2><<<g2, blk, 0, stream>>>((const float2*)A, (float2*)nullptr, env, tw);
    }

    // A (Y buffer) is dead after inverse pass 2 -> safe to init misc region now,
    // which also produces wtab before grad_smooth needs it.
    init_scratch<<<16384, 256, 0, stream>>>(firstm, cnt, wtab);

    grad_smooth<<<dim3(512, BROWS), blk, 0, stream>>>(env, wtab, sm);

    edge_bits  <<<dim3(512, BROWS), blk, 0, stream>>>(sm, pebits, mebits);
    match_edges<<<256, blk, 0, stream>>>(pebits, mebits, cand_m, cand_ap, cnt, firstm);
    dedup_kept <<<dim3(64, BROWS), blk, 0, stream>>>(cand_m, cand_ap, cnt, firstm, env, keys, kcnt);
    select1    <<<dim3(16, BROWS), blk, 0, stream>>>(keys, kcnt, finalists);
    select2    <<<BROWS, blk, 0, stream>>>(finalists, out);
}

// Round 11
// 290.599 us; speedup vs baseline: 5.0385x; 1.1739x over previous
//
#include <hip/hip_runtime.h>
#include <cstdint>

// ---------------- constants ----------------
#define NFFT   131072
#define BROWS  32
#define PLEN   131071
#define NWORDS 2048       // 64-bit words per row of edge bits
#define CAPC   16384      // candidate / kept capacity per row
#define CSTR   32         // counter stride in ints (128 B) -> one cache line per row

// ================= twiddle table: tw[t] = (cos, sin)(2*pi*t/N) =================
// Symmetry: tw[t + N/2] = -tw[t] (exact negation) -> half the sincos calls.
__global__ __launch_bounds__(256) void setup_tw(double2* __restrict__ tw) {
    int t = blockIdx.x * 256 + threadIdx.x;           // [0, 65536)
    double ang = 6.283185307179586476925286766559 * ((double)t / 131072.0);
    double s, c;
    sincos(ang, &s, &c);
    tw[t] = make_double2(c, s);
    tw[t + 65536] = make_double2(-c, -s);
}

// ================= scratch init + gaussian weights (capture-safe) ===============
__global__ __launch_bounds__(256) void init_scratch(int* __restrict__ firstm,
                                                    int* __restrict__ cnt,
                                                    double* __restrict__ wtab) {
    __shared__ double tmp[21];
    int i = blockIdx.x * 256 + threadIdx.x;           // 4,194,304 ints
    firstm[i] = 0x7F7F7F7F;                           // BIG sentinel for scatter-min
    if (i < 2 * BROWS * CSTR) cnt[i] = 0;             // cnt[32*CSTR] + kcnt[32*CSTR]
    if (blockIdx.x == 0) {
        if (threadIdx.x < 21) {
            double sig = 19.0 / 6.0;
            double d = (double)((int)threadIdx.x - 10) / sig;
            tmp[threadIdx.x] = exp(-0.5 * (d * d));
        }
        __syncthreads();
        if (threadIdx.x < 21) {
            double s = 0.0;
            for (int j = 0; j < 21; ++j) s += tmp[j]; // same order as reference loop
            wtab[threadIdx.x] = tmp[threadIdx.x] / s;
        }
    }
}

__global__ __launch_bounds__(256) void zero_out(float* __restrict__ out, int n) {
    int i = blockIdx.x * 256 + threadIdx.x;
    if (i < n) out[i] = 0.0f;
}

// ================= FFT pass 1: 256-pt strided + inter-pass twiddle ==============
// Four-step N = 512*256, n = n2*512 + n1.  Inner DFT over n2 (len 256) for each
// column n1, multiply W_N^{DIR*n1*k2}, store Y[k2*512 + n1].
// DIR = -1: forward, real input x.   DIR = +1: inverse, complex input Zt where
// Zt[k2*512+k1] holds Z[k1*256+k2]  (so Z[m2*512+m1] = Zt[(m1&255)*512 + 2*m2 + (m1>>8)]).
// Global I/O cooperatively re-indexed for coalescing (round-9: load 16x->4x, store 4x->1x).
template<int DIR, typename CT>
__global__ __launch_bounds__(256) void fft_pass1(const float* __restrict__ xin,
                                                 const CT* __restrict__ zin,
                                                 CT* __restrict__ yout,
                                                 const double2* __restrict__ tw) {
    constexpr int L = 256, FPB = 4, T = 64, LH = 128;
    __shared__ double2 bufA[FPB][L];
    __shared__ double2 bufB[FPB][L];
    __shared__ double2 twL[255];
    const int b    = blockIdx.y;
    const int f    = threadIdx.x >> 6;
    const int tl   = threadIdx.x & 63;
    const int col0 = blockIdx.x * FPB;
    const int col  = col0 + f;                        // n1 / m1 in [0,512)

    if (threadIdx.x < 255) {                          // stage twiddles: twL[Ns-1+js]
        int ip = threadIdx.x + 1;
        int s  = 31 - __clz(ip);
        int js = ip - (1 << s);
        twL[threadIdx.x] = tw[js << (16 - s)];        // angle = pi*js/Ns
    }
    if constexpr (DIR == -1) {
        // cooperative coalesced load of tile x[0..255][col0..col0+3]
        const float* xr = xin + (size_t)b * NFFT;
        for (int r = 0; r < 4; ++r) {
            int t = (int)threadIdx.x + r * 256;       // [0,1024)
            int c = t & 3, row = t >> 2;
            bufA[c][row] = make_double2((double)xr[row * 512 + col0 + c], 0.0);
        }
    } else {
        // inverse gather: contiguous direction is m2 (stride 2 elems) -> keep fiber map
        const CT* zr = zin + (size_t)b * NFFT;
        int c1l = col & 255, c1h = col >> 8;
        for (int r = 0; r < L / T; ++r) {
            int m2 = tl + r * T;
            CT v = zr[c1l * 512 + 2 * m2 + c1h];
            bufA[f][m2] = make_double2((double)v.x, (double)v.y);
        }
    }
    __syncthreads();

    double2* src = bufA[f];
    double2* dst = bufB[f];
    int Ns = 1;
#pragma unroll
    for (int it = 0; it < 8; ++it) {
#pragma unroll
        for (int jj = 0; jj < LH / T; ++jj) {
            int j  = tl + jj * T;
            int js = j & (Ns - 1);
            double2 w = twL[Ns - 1 + js];
            double ws_ = (DIR < 0) ? -w.y : w.y;
            double2 v0 = src[j];
            double2 v1 = src[j + LH];
            double wr = v1.x * w.x - v1.y * ws_;
            double wi = v1.x * ws_ + v1.y * w.x;
            int idxD = ((j - js) << 1) + js;
            dst[idxD]      = make_double2(v0.x + wr, v0.y + wi);
            dst[idxD + Ns] = make_double2(v0.x - wr, v0.y - wi);
        }
        __syncthreads();
        double2* t2 = src; src = dst; dst = t2;
        Ns <<= 1;
    }
    // 8 iterations -> each fiber's result in bufA[f] (last syncthreads already done)
    // cooperative store: 4-lane groups write 4 consecutive double2 = 64 B lines
    CT* yr = yout + (size_t)b * NFFT;
    for (int r = 0; r < 4; ++r) {
        int t = (int)threadIdx.x + r * 256;           // [0,1024)
        int c = t & 3, k2 = t >> 2;
        int tt = ((col0 + c) * k2) & (NFFT - 1);
        double2 w = tw[tt];
        double ws_ = (DIR < 0) ? -w.y : w.y;
        double2 v = bufA[c][k2];
        CT o;
        o.x = (decltype(o.x))(v.x * w.x - v.y * ws_);
        o.y = (decltype(o.y))(v.x * ws_ + v.y * w.x);
        yr[(size_t)k2 * 512 + col0 + c] = o;
    }
}

// ================= FFT pass 2: 512-pt contiguous ==============
// DIR=-1: apply analytic-filter h(k), write Zt[k2*512+k1].
// DIR=+1: write env[c1*256+c2] = |a|/N (float), float2-coalesced across fibers.
template<int DIR, typename CT>
__global__ __launch_bounds__(256) void fft_pass2(const CT* __restrict__ yin,
                                                 CT* __restrict__ ztout,
                                                 float* __restrict__ envout,
                                                 const double2* __restrict__ tw) {
    constexpr int L = 512, FPB = 2, T = 128, LH = 256;
    __shared__ double2 bufA[FPB][L];
    __shared__ double2 bufB[FPB][L];
    __shared__ double2 twL[511];
    const int b  = blockIdx.y;
    const int f  = threadIdx.x >> 7;
    const int tl = threadIdx.x & 127;
    const int k2 = blockIdx.x * FPB + f;              // [0,256)

    for (int i = threadIdx.x; i < 511; i += 256) {
        int ip = i + 1;
        int s  = 31 - __clz(ip);
        int js = ip - (1 << s);
        twL[i] = tw[js << (16 - s)];
    }
    const CT* yr = yin + (size_t)b * NFFT + (size_t)k2 * 512;
    for (int r = 0; r < L / T; ++r) {
        int i = tl + r * T;
        CT v = yr[i];
        bufA[f][i] = make_double2((double)v.x, (double)v.y);
    }
    __syncthreads();

    double2* src = bufA[f];
    double2* dst = bufB[f];
    int Ns = 1;
#pragma unroll
    for (int it = 0; it < 9; ++it) {
#pragma unroll
        for (int jj = 0; jj < LH / T; ++jj) {
            int j  = tl + jj * T;
            int js = j & (Ns - 1);
            double2 w = twL[Ns - 1 + js];
            double ws_ = (DIR < 0) ? -w.y : w.y;
            double2 v0 = src[j];
            double2 v1 = src[j + LH];
            double wr = v1.x * w.x - v1.y * ws_;
            double wi = v1.x * ws_ + v1.y * w.x;
            int idxD = ((j - js) << 1) + js;
            dst[idxD]      = make_double2(v0.x + wr, v0.y + wi);
            dst[idxD + Ns] = make_double2(v0.x - wr, v0.y - wi);
        }
        __syncthreads();
        double2* t2 = src; src = dst; dst = t2;
        Ns <<= 1;
    }
    // 9 iterations (odd) -> each fiber's result in bufB[f] (already synced)
    if constexpr (DIR == -1) {
        CT* zr = ztout + (size_t)b * NFFT + (size_t)k2 * 512;
        for (int r = 0; r < L / T; ++r) {
            int k1 = tl + r * T;
            int k  = k1 * 256 + k2;
            double hm = (k == 0 || k == 65536) ? 1.0 : (k < 65536 ? 2.0 : 0.0);
            double2 v = src[k1];
            CT o;
            o.x = (decltype(o.x))(v.x * hm);
            o.y = (decltype(o.y))(v.y * hm);
            zr[k1] = o;
        }
    } else {
        float* er = envout + (size_t)b * NFFT;
        int k20 = blockIdx.x * FPB;
        for (int r = 0; r < 2; ++r) {
            int c1 = (int)threadIdx.x + r * 256;      // [0,512)
            double2 v0 = bufB[0][c1];
            double2 v1 = bufB[1][c1];
            float2 o;
            o.x = (float)(sqrt(v0.x * v0.x + v0.y * v0.y) * (1.0 / 131072.0));
            o.y = (float)(sqrt(v1.x * v1.x + v1.y * v1.y) * (1.0 / 131072.0));
            *(float2*)&er[(size_t)c1 * 256 + k20] = o;
        }
    }
}

// ================= gradient + 21-tap gaussian smoothing =================
__global__ __launch_bounds__(256) void grad_smooth(const float* __restrict__ env,
                                                   const double* __restrict__ wtab,
                                                   float* __restrict__ sm) {
    __shared__ float  e[280];
    __shared__ double g[278];
    __shared__ double w[21];
    const int b  = blockIdx.y;
    const int n0 = blockIdx.x * 256;
    const float* er = env + (size_t)b * NFFT;
    if (threadIdx.x < 21) w[threadIdx.x] = wtab[threadIdx.x];
    for (int i = threadIdx.x; i < 278; i += 256) {
        int q = n0 - 11 + i;
        e[i] = er[min(max(q, 0), NFFT - 1)];
    }
    __syncthreads();
    for (int i = threadIdx.x + 1; i < 277; i += 256) {
        int q = n0 - 11 + i;
        double gv;
        if (q < 0 || q > NFFT - 1)   gv = 0.0;
        else if (q == 0)             gv = ((double)e[i + 1] - (double)e[i])     / 10.0;
        else if (q == NFFT - 1)      gv = ((double)e[i]     - (double)e[i - 1]) / 10.0;
        else                         gv = ((double)e[i + 1] - (double)e[i - 1]) / 20.0;
        g[i] = gv;
    }
    __syncthreads();
    double acc = 0.0;
#pragma unroll
    for (int d = 0; d < 21; ++d)
        acc += w[d] * g[threadIdx.x + 1 + d];
    sm[(size_t)b * NFFT + n0 + threadIdx.x] = (float)acc;
}

// ================= rising-edge bitmasks (f32 compare == reference promotion) =====
__global__ __launch_bounds__(256) void edge_bits(const float* __restrict__ sm,
                                                 unsigned long long* __restrict__ pebits,
                                                 unsigned long long* __restrict__ mebits) {
    const int b = blockIdx.y;
    const int m = blockIdx.x * 256 + threadIdx.x;
    const float* g = sm + (size_t)b * NFFT;
    bool pe = false, me = false;
    if (m < PLEN) {
        float g0 = g[m], g1 = g[m + 1];
        pe = (g1 >  0.01f)   && !(g0 >  0.01f);
        me = (g1 < -0.0025f) && !(g0 < -0.0025f);
    }
    unsigned long long pw = __ballot(pe);
    unsigned long long mw = __ballot(me);
    if ((threadIdx.x & 63) == 0) {
        int wi = m >> 6;
        pebits[b * NWORDS + wi] = pw;
        mebits[b * NWORDS + wi] = mw;
    }
}

// ======= backward scan: nearest plus edge at position <= m, window-limited =======
__device__ __forceinline__ int find_plus(const unsigned long long* __restrict__ pb,
                                         int w, int bit, int m) {
    int lowpos = m - 599;                              // gap<600 -> p >= m-599
    int wi = w;
    unsigned long long pw = pb[wi] & ((bit == 63) ? ~0ull : ((1ull << (bit + 1)) - 1ull));
    while (true) {
        if (pw) return wi * 64 + 63 - __clzll(pw);
        --wi;
        if (wi < 0 || wi * 64 + 63 < lowpos) return -1;
        pw = pb[wi];
    }
}

// ================= match minus edges to nearest preceding plus edge =============
// Wave-aggregated compaction: count -> wave prefix-sum -> ONE atomicAdd per wave.
__global__ __launch_bounds__(256) void match_edges(const unsigned long long* __restrict__ pebits,
                                                   const unsigned long long* __restrict__ mebits,
                                                   int* __restrict__ cand_m,
                                                   int* __restrict__ cand_ap,
                                                   int* __restrict__ cnt,
                                                   int* __restrict__ firstm) {
    int gid = blockIdx.x * 256 + threadIdx.x;         // 65536 = 32 rows * 2048 words
    int b = gid >> 11, w = gid & (NWORDS - 1);        // wave never straddles rows (64|2048)
    int lane = threadIdx.x & 63;
    const unsigned long long mw0 = mebits[b * NWORDS + w];
    const unsigned long long* pb = pebits + b * NWORDS;

    // pass A: count valid candidates in this word
    int myc = 0;
    unsigned long long mw = mw0;
    while (mw) {
        int bit = __ffsll(mw) - 1;
        mw &= mw - 1;
        int m = w * 64 + bit;
        int p = find_plus(pb, w, bit, m);
        if (p >= 0) {
            int gap = m - p;
            if (gap > 12 && gap < 600) ++myc;
        }
    }

    // inclusive wave-wide prefix sum of myc
    int scan = myc;
#pragma unroll
    for (int off = 1; off < 64; off <<= 1) {
        int v = __shfl_up(scan, off, 64);
        if (lane >= off) scan += v;
    }
    int total = __shfl(scan, 63, 64);
    int base = 0;
    if (total > 0) {
        if (lane == 63) base = atomicAdd(&cnt[b * CSTR], total);
        base = __shfl(base, 63, 64);
    }
    int idx = base + scan - myc;                      // this thread's exclusive offset

    // pass B: re-scan, write candidates, scatter-min for dedup
    mw = mw0;
    while (mw) {
        int bit = __ffsll(mw) - 1;
        mw &= mw - 1;
        int m = w * 64 + bit;
        int p = find_plus(pb, w, bit, m);
        if (p >= 0) {
            int gap = m - p;
            if (gap > 12 && gap < 600) {
                if (idx < CAPC) {
                    cand_m [b * CAPC + idx] = m;
                    cand_ap[b * CAPC + idx] = p;
                    atomicMin(&firstm[(size_t)b * NFFT + p], m);   // fire-and-forget
                }
                ++idx;
            }
        }
    }
}

// ================= dedup (first minus per plus) -> sort keys =================
// Ballot-aggregated: one atomicAdd per wave instead of one per kept entry.
__global__ __launch_bounds__(256) void dedup_kept(const int* __restrict__ cand_m,
                                                  const int* __restrict__ cand_ap,
                                                  const int* __restrict__ cnt,
                                                  const int* __restrict__ firstm,
                                                  const float* __restrict__ env,
                                                  unsigned long long* __restrict__ keys,
                                                  int* __restrict__ kcnt) {
    const int b = blockIdx.y;
    const int i = blockIdx.x * 256 + threadIdx.x;
    const int lane = threadIdx.x & 63;
    int n = min(cnt[b * CSTR], CAPC);

    bool kept = false;
    unsigned long long key = 0;
    if (i < n) {
        int m  = cand_m [b * CAPC + i];
        int ap = cand_ap[b * CAPC + i];
        if (firstm[(size_t)b * NFFT + ap] == m) {
            float amp = env[(size_t)b * NFFT + m];
            unsigned int ab = __float_as_uint(amp);    // amp >= 0
            key = ((unsigned long long)(~ab) << 32) | (unsigned int)m;
            kept = true;
        }
    }
    unsigned long long bal = __ballot(kept);
    int tot = __popcll(bal);
    if (tot > 0) {
        int base = 0;
        if (lane == 0) base = atomicAdd(&kcnt[b * CSTR], tot);
        base = __shfl(base, 0, 64);
        if (kept) {
            int off = __popcll(bal & ((lane == 0) ? 0ull : ((1ull << lane) - 1ull)));
            int j = base + off;
            if (j < CAPC) keys[(size_t)b * CAPC + j] = key;
        }
    }
}

// ================= tier-1 selection: top-32 of each 1024-chunk =================
__global__ __launch_bounds__(256) void select1(const unsigned long long* __restrict__ keys,
                                               const int* __restrict__ kcnt,
                                               unsigned long long* __restrict__ finalists) {
    __shared__ unsigned long long sk[1024];
    const int b = blockIdx.y, ch = blockIdx.x;
    int n = min(kcnt[b * CSTR], CAPC);
    for (int r = 0; r < 4; ++r) {
        int i = r * 256 + threadIdx.x;
        int slot = ch * 1024 + i;
        sk[i] = (slot < n) ? keys[(size_t)b * CAPC + slot] : ~0ull;
    }
    __syncthreads();
    for (int size = 2; size <= 1024; size <<= 1) {
        for (int stride = size >> 1; stride > 0; stride >>= 1) {
            for (int r = 0; r < 4; ++r) {
                int i = r * 256 + threadIdx.x;
                int j = i ^ stride;
                if (j > i) {
                    bool up = ((i & size) == 0);
                    unsigned long long a = sk[i], c = sk[j];
                    if ((a > c) == up) { sk[i] = c; sk[j] = a; }
                }
            }
            __syncthreads();
        }
    }
    if (threadIdx.x < 32)
        finalists[((size_t)b * 16 + ch) * 32 + threadIdx.x] = sk[threadIdx.x];
}

// ================= tier-2: merge 16*32 finalists, output row =================
// Tail is wave-parallel rank-placement (round-10 profile: serial thread-0 insertion
// sort on a runtime-indexed local array = scratch memory = 68 us of the 341 total).
// After ascending bitonic: valid keys are the prefix sk[0..nsel-1]; m's are unique
// (each minus edge maps to exactly one plus edge) -> rank by m is a bijection.
__global__ __launch_bounds__(256) void select2(const unsigned long long* __restrict__ finalists,
                                               float* __restrict__ out) {
    __shared__ unsigned long long sk[512];
    const int b = blockIdx.x;
    for (int r = 0; r < 2; ++r) {
        int i = r * 256 + threadIdx.x;
        sk[i] = finalists[(size_t)b * 512 + i];
    }
    __syncthreads();
    for (int size = 2; size <= 512; size <<= 1) {
        for (int stride = size >> 1; stride > 0; stride >>= 1) {
            for (int r = 0; r < 2; ++r) {
                int i = r * 256 + threadIdx.x;
                int j = i ^ stride;
                if (j > i) {
                    bool up = ((i & size) == 0);
                    unsigned long long a = sk[i], c = sk[j];
                    if ((a > c) == up) { sk[i] = c; sk[j] = a; }
                }
            }
            __syncthreads();
        }
    }
    if (threadIdx.x < 64) {                            // wave 0 only, fully active
        int lane = (int)threadIdx.x;
        unsigned long long key = (lane < 32) ? sk[lane] : ~0ull;
        bool valid = (key != ~0ull);
        int m = valid ? (int)(unsigned int)(key & 0xffffffffu) : 0x7fffffff;
        unsigned long long bal = __ballot(valid);
        int nsel = __popcll(bal);
        int rank = 0;
#pragma unroll
        for (int j = 0; j < 32; ++j) {
            int mj = __shfl(m, j, 64);
            rank += (mj < m) ? 1 : 0;                  // m unique; invalid = +inf
        }
        if (lane < 32 - nsel) out[b * 32 + lane] = 0.0f;
        if (valid)            out[b * 32 + (32 - nsel) + rank] = (float)m;
    }
}

// =========================== launch ===========================
extern "C" void kernel_launch(void* const* d_in, const int* in_sizes, int n_in,
                              void* d_out, int out_size, void* d_ws, size_t ws_size,
                              hipStream_t stream) {
    const float* x = (const float*)d_in[0];
    float* out = (float*)d_out;
    char* ws = (char*)d_ws;

    const size_t TWB = 2097152;                        // 131072 * 16 bytes
    const size_t S_F = 33554432;                       // float2[32][131072]
    const size_t S_D = 67108864;                       // double2[32][131072]
    bool dbl = ws_size >= TWB + 2 * S_D;
    size_t S = dbl ? S_D : S_F;
    if (ws_size < TWB + 2 * S_F) {                     // workspace too small: bail cleanly
        zero_out<<<(out_size + 255) / 256, 256, 0, stream>>>(out, out_size);
        return;
    }

    double2* tw = (double2*)ws;
    char* A  = ws + TWB;                               // Y, then Y2, then misc
    char* Bz = A + S;                                  // Zt, then env+sm
    float* env = (float*)Bz;
    float* sm  = (float*)(Bz + 16777216);
    // misc region (inside A, alive only after inverse pass 2):
    int* firstm = (int*)A;                                                  // 16 MB
    unsigned long long* pebits = (unsigned long long*)(A + 16777216);       // 512 KB
    unsigned long long* mebits = (unsigned long long*)(A + 16777216 + 524288);
    int* cand_m  = (int*)(A + 17825792);                                    // 2 MB
    int* cand_ap = (int*)(A + 19922944);                                    // 2 MB
    unsigned long long* keys      = (unsigned long long*)(A + 22020096);    // 4 MB
    unsigned long long* finalists = (unsigned long long*)(A + 26214400);    // 128 KB
    int* cnt  = (int*)(A + 27262976);                  // 32*CSTR ints (1 line per row)
    int* kcnt = cnt + BROWS * CSTR;                    // 32*CSTR ints
    double* wtab = (double*)(A + 27271168);            // 21 gaussian weights

    setup_tw<<<256, 256, 0, stream>>>(tw);             // halved via tw[t+N/2] = -tw[t]

    dim3 g1(128, BROWS), g2(128, BROWS), blk(256);
    if (dbl) {
        fft_pass1<-1, double2><<<g1, blk, 0, stream>>>(x, (const double2*)nullptr, (double2*)A, tw);
        fft_pass2<-1, double2><<<g2, blk, 0, stream>>>((const double2*)A, (double2*)Bz, (float*)nullptr, tw);
        fft_pass1<+1, double2><<<g1, blk, 0, stream>>>((const float*)nullptr, (const double2*)Bz, (double2*)A, tw);
        fft_pass2<+1, double2><<<g2, blk, 0, stream>>>((const double2*)A, (double2*)nullptr, env, tw);
    } else {
        fft_pass1<-1, float2><<<g1, blk, 0, stream>>>(x, (const float2*)nullptr, (float2*)A, tw);
        fft_pass2<-1, float2><<<g2, blk, 0, stream>>>((const float2*)A, (float2*)Bz, (float*)nullptr, tw);
        fft_pass1<+1, float2><<<g1, blk, 0, stream>>>((const float*)nullptr, (const float2*)Bz, (float2*)A, tw);
        fft_pass2<+1, float2><<<g2, blk, 0, stream>>>((const float2*)A, (float2*)nullptr, env, tw);
    }

    // A (Y buffer) is dead after inverse pass 2 -> safe to init misc region now,
    // which also produces wtab before grad_smooth needs it.
    init_scratch<<<16384, 256, 0, stream>>>(firstm, cnt, wtab);

    grad_smooth<<<dim3(512, BROWS), blk, 0, stream>>>(env, wtab, sm);

    edge_bits  <<<dim3(512, BROWS), blk, 0, stream>>>(sm, pebits, mebits);
    match_edges<<<256, blk, 0, stream>>>(pebits, mebits, cand_m, cand_ap, cnt, firstm);
    dedup_kept <<<dim3(64, BROWS), blk, 0, stream>>>(cand_m, cand_ap, cnt, firstm, env, keys, kcnt);
    select1    <<<dim3(16, BROWS), blk, 0, stream>>>(keys, kcnt, finalists);
    select2    <<<BROWS, blk, 0, stream>>>(finalists, out);
}